// Round 1
// baseline (7424.424 us; speedup 1.0000x reference)
//
#include <hip/hip_runtime.h>
#include <cstddef>

#define N_NODES 50000
#define N_EDGES 800000
static constexpr float BN_EPS = 1e-5f;

// ---------------- utility: zero fill (graph-capture safe) ----------------
__global__ void fill_zero(float* __restrict__ p, int n4) {
    float4* p4 = (float4*)p;
    for (int i = blockIdx.x * blockDim.x + threadIdx.x; i < n4; i += gridDim.x * blockDim.x)
        p4[i] = make_float4(0.f, 0.f, 0.f, 0.f);
}

// ---------------- degree ----------------
__global__ void deg_kernel(const int* __restrict__ dst, float* __restrict__ deg, int E) {
    int i = blockIdx.x * blockDim.x + threadIdx.x;
    if (i < E) atomicAdd(&deg[dst[i]], 1.0f);
}

__global__ void inv_kernel(const float* __restrict__ deg, float* __restrict__ inv, int n) {
    int i = blockIdx.x * blockDim.x + threadIdx.x;
    if (i < n) inv[i] = 1.0f / fmaxf(deg[i], 1.0f);
}

// ---------------- scatter-add aggregation ----------------
// thread handles (edge e, 4-feature chunk c); consecutive threads -> consecutive c
template <int D>
__global__ __launch_bounds__(256) void scatter_add(const float* __restrict__ X,
                                                   const int* __restrict__ src,
                                                   const int* __restrict__ dst,
                                                   float* __restrict__ S, int E) {
    constexpr int C = D / 4;
    int tid = blockIdx.x * blockDim.x + threadIdx.x;
    int e = tid / C;
    int c = tid % C;
    if (e >= E) return;
    int sn = src[e];
    int dn = dst[e];
    const float4* X4 = (const float4*)X;
    float4 v = X4[(size_t)sn * C + c];
    float* o = S + (size_t)dn * D + c * 4;
    atomicAdd(o + 0, v.x);
    atomicAdd(o + 1, v.y);
    atomicAdd(o + 2, v.z);
    atomicAdd(o + 3, v.w);
}

// ---------------- fused SAGE linear: H = (S*inv)@Wl + bl + X@Wr ----------------
template <int K, int M>
__global__ __launch_bounds__(256) void sage_linear(const float* __restrict__ S,
                                                   const float* __restrict__ inv_deg,
                                                   const float* __restrict__ X,
                                                   const float* __restrict__ Wl,
                                                   const float* __restrict__ bl,
                                                   const float* __restrict__ Wr,
                                                   float* __restrict__ H) {
    constexpr int BR = 16;          // rows per block
    constexpr int JG = M / 4;       // column groups (float4)
    constexpr int RG = 256 / JG;    // row groups
    constexpr int RPT = BR / RG;    // rows per thread
    __shared__ float As[BR][K];
    __shared__ float Ax[BR][K];
    const int t = threadIdx.x;
    const int row0 = blockIdx.x * BR;

    constexpr int TOT4 = BR * (K / 4);
    const float4* S4 = (const float4*)S;
    const float4* X4 = (const float4*)X;
    for (int idx = t; idx < TOT4; idx += 256) {
        int r = idx / (K / 4), c = idx % (K / 4);
        int row = row0 + r;
        float idg = inv_deg[row];
        float4 sv = S4[(size_t)row * (K / 4) + c];
        float4 xv = X4[(size_t)row * (K / 4) + c];
        As[r][c * 4 + 0] = sv.x * idg;
        As[r][c * 4 + 1] = sv.y * idg;
        As[r][c * 4 + 2] = sv.z * idg;
        As[r][c * 4 + 3] = sv.w * idg;
        Ax[r][c * 4 + 0] = xv.x;
        Ax[r][c * 4 + 1] = xv.y;
        Ax[r][c * 4 + 2] = xv.z;
        Ax[r][c * 4 + 3] = xv.w;
    }
    __syncthreads();

    const int tj = t % JG;
    const int r0 = (t / JG) * RPT;
    const float4* Wl4 = (const float4*)Wl;
    const float4* Wr4 = (const float4*)Wr;
    float4 bv = ((const float4*)bl)[tj];

    float acc[RPT][4];
#pragma unroll
    for (int r = 0; r < RPT; ++r) {
        acc[r][0] = bv.x; acc[r][1] = bv.y; acc[r][2] = bv.z; acc[r][3] = bv.w;
    }

    for (int k = 0; k < K; ++k) {
        float4 wl = Wl4[k * JG + tj];
        float4 wr = Wr4[k * JG + tj];
#pragma unroll
        for (int r = 0; r < RPT; ++r) {
            float a = As[r0 + r][k];
            float b = Ax[r0 + r][k];
            acc[r][0] = fmaf(a, wl.x, fmaf(b, wr.x, acc[r][0]));
            acc[r][1] = fmaf(a, wl.y, fmaf(b, wr.y, acc[r][1]));
            acc[r][2] = fmaf(a, wl.z, fmaf(b, wr.z, acc[r][2]));
            acc[r][3] = fmaf(a, wl.w, fmaf(b, wr.w, acc[r][3]));
        }
    }

    float4* H4 = (float4*)H;
#pragma unroll
    for (int r = 0; r < RPT; ++r) {
        int row = row0 + r0 + r;
        H4[(size_t)row * JG + tj] = make_float4(acc[r][0], acc[r][1], acc[r][2], acc[r][3]);
    }
}

// ---------------- BN column stats ----------------
template <int M>
__global__ __launch_bounds__(256) void col_stats(const float* __restrict__ H,
                                                 float* __restrict__ sums,
                                                 float* __restrict__ sumsq, int nrows) {
    constexpr int G = 256 / M;
    int j = threadIdx.x % M;
    int rg = threadIdx.x / M;
    float s = 0.f, ss = 0.f;
    for (int r = blockIdx.x * G + rg; r < nrows; r += gridDim.x * G) {
        float v = H[(size_t)r * M + j];
        s += v;
        ss += v * v;
    }
    atomicAdd(&sums[j], s);
    atomicAdd(&sumsq[j], ss);
}

template <int M>
__global__ void bn_finalize(const float* __restrict__ sums, const float* __restrict__ sumsq,
                            const float* __restrict__ g, const float* __restrict__ beta,
                            float* __restrict__ scale, float* __restrict__ shift, int nrows) {
    int j = threadIdx.x;
    if (j >= M) return;
    float mean = sums[j] / nrows;
    float var = fmaxf(sumsq[j] / nrows - mean * mean, 0.f);
    float sc = g[j] * rsqrtf(var + BN_EPS);
    scale[j] = sc;
    shift[j] = beta[j] - mean * sc;
}

template <int M>
__global__ __launch_bounds__(256) void bn_relu(float* __restrict__ H,
                                               const float* __restrict__ scale,
                                               const float* __restrict__ shift, int n4) {
    float4* H4 = (float4*)H;
    const float4* sc4 = (const float4*)scale;
    const float4* sh4 = (const float4*)shift;
    for (int i = blockIdx.x * blockDim.x + threadIdx.x; i < n4; i += gridDim.x * blockDim.x) {
        int j4 = i % (M / 4);
        float4 v = H4[i];
        float4 a = sc4[j4];
        float4 b = sh4[j4];
        v.x = fmaxf(fmaf(v.x, a.x, b.x), 0.f);
        v.y = fmaxf(fmaf(v.y, a.y, b.y), 0.f);
        v.z = fmaxf(fmaf(v.z, a.z, b.z), 0.f);
        v.w = fmaxf(fmaf(v.w, a.w, b.w), 0.f);
        H4[i] = v;
    }
}

// ---------------- head: out = H3 @ wh + bh ----------------
__global__ __launch_bounds__(256) void head_kernel(const float* __restrict__ H3,
                                                   const float* __restrict__ wh,
                                                   const float* __restrict__ bh,
                                                   float* __restrict__ out, int n) {
    int i = blockIdx.x * blockDim.x + threadIdx.x;
    if (i >= n) return;
    const float4* h4 = (const float4*)(H3 + (size_t)i * 64);
    const float4* w4 = (const float4*)wh;
    float acc = bh[0];
#pragma unroll
    for (int c = 0; c < 16; ++c) {
        float4 v = h4[c];
        float4 w = w4[c];
        acc += v.x * w.x + v.y * w.y + v.z * w.z + v.w * w.w;
    }
    out[i] = acc;
}

// ---------------- launch ----------------
extern "C" void kernel_launch(void* const* d_in, const int* in_sizes, int n_in,
                              void* d_out, int out_size, void* d_ws, size_t ws_size,
                              hipStream_t stream) {
    const int N = N_NODES, E = N_EDGES;
    const float* x   = (const float*)d_in[0];
    const int*   ei  = (const int*)d_in[1];
    const int*   src = ei;
    const int*   dst = ei + E;
    const float* w1l = (const float*)d_in[2];
    const float* b1l = (const float*)d_in[3];
    const float* w1r = (const float*)d_in[4];
    const float* g1  = (const float*)d_in[5];
    const float* be1 = (const float*)d_in[6];
    const float* w2l = (const float*)d_in[7];
    const float* b2l = (const float*)d_in[8];
    const float* w2r = (const float*)d_in[9];
    const float* g2  = (const float*)d_in[10];
    const float* be2 = (const float*)d_in[11];
    const float* w3l = (const float*)d_in[12];
    const float* b3l = (const float*)d_in[13];
    const float* w3r = (const float*)d_in[14];
    const float* g3  = (const float*)d_in[15];
    const float* be3 = (const float*)d_in[16];
    const float* wh  = (const float*)d_in[17];
    const float* bh  = (const float*)d_in[18];
    float* out = (float*)d_out;

    float* ws   = (float*)d_ws;
    float* deg  = ws;                       // N
    float* inv  = ws + N;                   // N
    float* sbuf = ws + 2 * (size_t)N;       // N*256
    float* h1   = sbuf + 256 * (size_t)N;   // N*256
    float* h2   = h1 + 256 * (size_t)N;     // N*128
    float* h3   = h2 + 128 * (size_t)N;     // N*64
    float* stat = h3 + 64 * (size_t)N;      // 1024
    float* sums = stat, *sumsq = stat + 256, *scale = stat + 512, *shift = stat + 768;

    auto zero = [&](float* p, size_t nfloats) {
        int n4 = (int)(nfloats / 4);
        int blocks = (n4 + 255) / 256;
        if (blocks > 4096) blocks = 4096;
        fill_zero<<<blocks, 256, 0, stream>>>(p, n4);
    };

    // degree / inverse degree
    zero(deg, N);
    deg_kernel<<<(E + 255) / 256, 256, 0, stream>>>(dst, deg, E);
    inv_kernel<<<(N + 255) / 256, 256, 0, stream>>>(deg, inv, N);

    // ---- layer 1: 256 -> 256 ----
    zero(sbuf, (size_t)N * 256);
    scatter_add<256><<<(E * 64 + 255) / 256, 256, 0, stream>>>(x, src, dst, sbuf, E);
    sage_linear<256, 256><<<N / 16, 256, 0, stream>>>(sbuf, inv, x, w1l, b1l, w1r, h1);
    zero(sums, 512);
    col_stats<256><<<256, 256, 0, stream>>>(h1, sums, sumsq, N);
    bn_finalize<256><<<1, 256, 0, stream>>>(sums, sumsq, g1, be1, scale, shift, N);
    bn_relu<256><<<2048, 256, 0, stream>>>(h1, scale, shift, N * 256 / 4);

    // ---- layer 2: 256 -> 128 ----
    zero(sbuf, (size_t)N * 256);
    scatter_add<256><<<(E * 64 + 255) / 256, 256, 0, stream>>>(h1, src, dst, sbuf, E);
    sage_linear<256, 128><<<N / 16, 256, 0, stream>>>(sbuf, inv, h1, w2l, b2l, w2r, h2);
    zero(sums, 512);
    col_stats<128><<<256, 256, 0, stream>>>(h2, sums, sumsq, N);
    bn_finalize<128><<<1, 128, 0, stream>>>(sums, sumsq, g2, be2, scale, shift, N);
    bn_relu<128><<<2048, 256, 0, stream>>>(h2, scale, shift, N * 128 / 4);

    // ---- layer 3: 128 -> 64 ----
    zero(sbuf, (size_t)N * 128);
    scatter_add<128><<<(E * 32 + 255) / 256, 256, 0, stream>>>(h2, src, dst, sbuf, E);
    sage_linear<128, 64><<<N / 16, 256, 0, stream>>>(sbuf, inv, h2, w3l, b3l, w3r, h3);
    zero(sums, 512);
    col_stats<64><<<256, 256, 0, stream>>>(h3, sums, sumsq, N);
    bn_finalize<64><<<1, 64, 0, stream>>>(sums, sumsq, g3, be3, scale, shift, N);
    bn_relu<64><<<2048, 256, 0, stream>>>(h3, scale, shift, N * 64 / 4);

    // ---- head ----
    head_kernel<<<(N + 255) / 256, 256, 0, stream>>>(h3, wh, bh, out, N);
}

// Round 2
// 1160.388 us; speedup vs baseline: 6.3982x; 6.3982x over previous
//
#include <hip/hip_runtime.h>
#include <cstddef>

#define N_NODES 50000
#define N_EDGES 800000
static constexpr float BN_EPS = 1e-5f;

// ---------------- utility: zero fill (graph-capture safe) ----------------
__global__ void fill_zero(float* __restrict__ p, int n4) {
    float4* p4 = (float4*)p;
    for (int i = blockIdx.x * blockDim.x + threadIdx.x; i < n4; i += gridDim.x * blockDim.x)
        p4[i] = make_float4(0.f, 0.f, 0.f, 0.f);
}

// ---------------- CSR build ----------------
__global__ void deg_count(const int* __restrict__ dst, int* __restrict__ deg, int E) {
    int i = blockIdx.x * blockDim.x + threadIdx.x;
    if (i < E) atomicAdd(&deg[dst[i]], 1);
}

// single-block exclusive scan over deg[0..n) -> rowptr[0..n]
__global__ __launch_bounds__(1024) void scan_kernel(const int* __restrict__ deg,
                                                    int* __restrict__ rowptr, int n) {
    __shared__ int s[1024];
    const int t = threadIdx.x;
    const int CH = (n + 1023) / 1024;
    const int b = t * CH;
    const int e = min(b + CH, n);
    int sum = 0;
    for (int i = b; i < e; ++i) sum += deg[i];
    s[t] = sum;
    __syncthreads();
    for (int off = 1; off < 1024; off <<= 1) {
        int v = (t >= off) ? s[t - off] : 0;
        __syncthreads();
        s[t] += v;
        __syncthreads();
    }
    int base = (t == 0) ? 0 : s[t - 1];
    for (int i = b; i < e; ++i) { rowptr[i] = base; base += deg[i]; }
    if (t == 1023) rowptr[n] = base;
}

__global__ void inv_from_deg(const int* __restrict__ deg, float* __restrict__ inv, int n) {
    int i = blockIdx.x * blockDim.x + threadIdx.x;
    if (i < n) inv[i] = 1.0f / fmaxf((float)deg[i], 1.0f);
}

__global__ void csr_fill(const int* __restrict__ src, const int* __restrict__ dst,
                         const int* __restrict__ rowptr, int* __restrict__ cursor,
                         int* __restrict__ csr, int E) {
    int e = blockIdx.x * blockDim.x + threadIdx.x;
    if (e >= E) return;
    int d = dst[e];
    int p = atomicAdd(&cursor[d], 1);
    csr[rowptr[d] + p] = src[e];
}

// ---------------- gather-mean aggregation ----------------
// C4 = D/4 float4-chunks per row; 256/C4 nodes per block; one C4-lane group per node
template <int C4>
__global__ __launch_bounds__(256) void gather_mean(const float* __restrict__ X,
                                                   const int* __restrict__ rowptr,
                                                   const int* __restrict__ csr,
                                                   const float* __restrict__ inv,
                                                   float* __restrict__ S, int N) {
    constexpr int NPB = 256 / C4;
    const int lane = threadIdx.x % C4;
    const int node = blockIdx.x * NPB + threadIdx.x / C4;
    if (node >= N) return;
    const int beg = rowptr[node];
    const int end = rowptr[node + 1];
    const float4* X4 = (const float4*)X;
    float4 acc = make_float4(0.f, 0.f, 0.f, 0.f);
    int k = beg;
    for (; k + 1 < end; k += 2) {
        int s0 = csr[k], s1 = csr[k + 1];
        float4 a = X4[(size_t)s0 * C4 + lane];
        float4 b = X4[(size_t)s1 * C4 + lane];
        acc.x += a.x + b.x;
        acc.y += a.y + b.y;
        acc.z += a.z + b.z;
        acc.w += a.w + b.w;
    }
    if (k < end) {
        int s0 = csr[k];
        float4 a = X4[(size_t)s0 * C4 + lane];
        acc.x += a.x; acc.y += a.y; acc.z += a.z; acc.w += a.w;
    }
    float w = inv[node];
    ((float4*)S)[(size_t)node * C4 + lane] =
        make_float4(acc.x * w, acc.y * w, acc.z * w, acc.w * w);
}

// ---------------- fused SAGE linear: H = A@Wl + bl + X@Wr (A pre-normalized) ----------------
template <int K, int M>
__global__ __launch_bounds__(256) void sage_linear(const float* __restrict__ S,
                                                   const float* __restrict__ X,
                                                   const float* __restrict__ Wl,
                                                   const float* __restrict__ bl,
                                                   const float* __restrict__ Wr,
                                                   float* __restrict__ H) {
    constexpr int BR = 16;          // rows per block
    constexpr int JG = M / 4;       // column groups (float4)
    constexpr int RG = 256 / JG;    // row groups
    constexpr int RPT = BR / RG;    // rows per thread
    __shared__ float As[BR][K];
    __shared__ float Ax[BR][K];
    const int t = threadIdx.x;
    const int row0 = blockIdx.x * BR;

    constexpr int TOT4 = BR * (K / 4);
    const float4* S4 = (const float4*)S;
    const float4* X4 = (const float4*)X;
    for (int idx = t; idx < TOT4; idx += 256) {
        int r = idx / (K / 4), c = idx % (K / 4);
        int row = row0 + r;
        float4 sv = S4[(size_t)row * (K / 4) + c];
        float4 xv = X4[(size_t)row * (K / 4) + c];
        As[r][c * 4 + 0] = sv.x;
        As[r][c * 4 + 1] = sv.y;
        As[r][c * 4 + 2] = sv.z;
        As[r][c * 4 + 3] = sv.w;
        Ax[r][c * 4 + 0] = xv.x;
        Ax[r][c * 4 + 1] = xv.y;
        Ax[r][c * 4 + 2] = xv.z;
        Ax[r][c * 4 + 3] = xv.w;
    }
    __syncthreads();

    const int tj = t % JG;
    const int r0 = (t / JG) * RPT;
    const float4* Wl4 = (const float4*)Wl;
    const float4* Wr4 = (const float4*)Wr;
    float4 bv = ((const float4*)bl)[tj];

    float acc[RPT][4];
#pragma unroll
    for (int r = 0; r < RPT; ++r) {
        acc[r][0] = bv.x; acc[r][1] = bv.y; acc[r][2] = bv.z; acc[r][3] = bv.w;
    }

    for (int k = 0; k < K; ++k) {
        float4 wl = Wl4[k * JG + tj];
        float4 wr = Wr4[k * JG + tj];
#pragma unroll
        for (int r = 0; r < RPT; ++r) {
            float a = As[r0 + r][k];
            float b = Ax[r0 + r][k];
            acc[r][0] = fmaf(a, wl.x, fmaf(b, wr.x, acc[r][0]));
            acc[r][1] = fmaf(a, wl.y, fmaf(b, wr.y, acc[r][1]));
            acc[r][2] = fmaf(a, wl.z, fmaf(b, wr.z, acc[r][2]));
            acc[r][3] = fmaf(a, wl.w, fmaf(b, wr.w, acc[r][3]));
        }
    }

    float4* H4 = (float4*)H;
#pragma unroll
    for (int r = 0; r < RPT; ++r) {
        int row = row0 + r0 + r;
        H4[(size_t)row * JG + tj] = make_float4(acc[r][0], acc[r][1], acc[r][2], acc[r][3]);
    }
}

// ---------------- BN column stats ----------------
template <int M>
__global__ __launch_bounds__(256) void col_stats(const float* __restrict__ H,
                                                 float* __restrict__ sums,
                                                 float* __restrict__ sumsq, int nrows) {
    constexpr int G = 256 / M;
    int j = threadIdx.x % M;
    int rg = threadIdx.x / M;
    float s = 0.f, ss = 0.f;
    for (int r = blockIdx.x * G + rg; r < nrows; r += gridDim.x * G) {
        float v = H[(size_t)r * M + j];
        s += v;
        ss += v * v;
    }
    atomicAdd(&sums[j], s);
    atomicAdd(&sumsq[j], ss);
}

template <int M>
__global__ void bn_finalize(const float* __restrict__ sums, const float* __restrict__ sumsq,
                            const float* __restrict__ g, const float* __restrict__ beta,
                            float* __restrict__ scale, float* __restrict__ shift, int nrows) {
    int j = threadIdx.x;
    if (j >= M) return;
    float mean = sums[j] / nrows;
    float var = fmaxf(sumsq[j] / nrows - mean * mean, 0.f);
    float sc = g[j] * rsqrtf(var + BN_EPS);
    scale[j] = sc;
    shift[j] = beta[j] - mean * sc;
}

template <int M>
__global__ __launch_bounds__(256) void bn_relu(float* __restrict__ H,
                                               const float* __restrict__ scale,
                                               const float* __restrict__ shift, int n4) {
    float4* H4 = (float4*)H;
    const float4* sc4 = (const float4*)scale;
    const float4* sh4 = (const float4*)shift;
    for (int i = blockIdx.x * blockDim.x + threadIdx.x; i < n4; i += gridDim.x * blockDim.x) {
        int j4 = i % (M / 4);
        float4 v = H4[i];
        float4 a = sc4[j4];
        float4 b = sh4[j4];
        v.x = fmaxf(fmaf(v.x, a.x, b.x), 0.f);
        v.y = fmaxf(fmaf(v.y, a.y, b.y), 0.f);
        v.z = fmaxf(fmaf(v.z, a.z, b.z), 0.f);
        v.w = fmaxf(fmaf(v.w, a.w, b.w), 0.f);
        H4[i] = v;
    }
}

// ---------------- head: out = H3 @ wh + bh ----------------
__global__ __launch_bounds__(256) void head_kernel(const float* __restrict__ H3,
                                                   const float* __restrict__ wh,
                                                   const float* __restrict__ bh,
                                                   float* __restrict__ out, int n) {
    int i = blockIdx.x * blockDim.x + threadIdx.x;
    if (i >= n) return;
    const float4* h4 = (const float4*)(H3 + (size_t)i * 64);
    const float4* w4 = (const float4*)wh;
    float acc = bh[0];
#pragma unroll
    for (int c = 0; c < 16; ++c) {
        float4 v = h4[c];
        float4 w = w4[c];
        acc += v.x * w.x + v.y * w.y + v.z * w.z + v.w * w.w;
    }
    out[i] = acc;
}

// ---------------- launch ----------------
extern "C" void kernel_launch(void* const* d_in, const int* in_sizes, int n_in,
                              void* d_out, int out_size, void* d_ws, size_t ws_size,
                              hipStream_t stream) {
    const int N = N_NODES, E = N_EDGES;
    const float* x   = (const float*)d_in[0];
    const int*   ei  = (const int*)d_in[1];
    const int*   src = ei;
    const int*   dst = ei + E;
    const float* w1l = (const float*)d_in[2];
    const float* b1l = (const float*)d_in[3];
    const float* w1r = (const float*)d_in[4];
    const float* g1  = (const float*)d_in[5];
    const float* be1 = (const float*)d_in[6];
    const float* w2l = (const float*)d_in[7];
    const float* b2l = (const float*)d_in[8];
    const float* w2r = (const float*)d_in[9];
    const float* g2  = (const float*)d_in[10];
    const float* be2 = (const float*)d_in[11];
    const float* w3l = (const float*)d_in[12];
    const float* b3l = (const float*)d_in[13];
    const float* w3r = (const float*)d_in[14];
    const float* g3  = (const float*)d_in[15];
    const float* be3 = (const float*)d_in[16];
    const float* wh  = (const float*)d_in[17];
    const float* bh  = (const float*)d_in[18];
    float* out = (float*)d_out;

    // ---- workspace layout ----
    char* wsb = (char*)d_ws;
    int* rowptr = (int*)wsb;                          // N+1 (padded to N+4)
    int* csr    = rowptr + (N + 4);                   // E
    float* inv  = (float*)(csr + E);                  // N
    float* sbuf = inv + N;                            // N*256
    float* h1   = sbuf + 256 * (size_t)N;             // N*256
    float* h2   = h1 + 256 * (size_t)N;               // N*128
    float* h3   = h2 + 128 * (size_t)N;               // N*64
    float* stat = h3 + 64 * (size_t)N;                // 1024
    float* sums = stat, *sumsq = stat + 256, *scale = stat + 512, *shift = stat + 768;
    // transient CSR-build scratch aliases sbuf (dead until first gather)
    int* deg_i  = (int*)sbuf;                         // N
    int* cursor = (int*)sbuf + N;                     // N

    auto zero = [&](void* p, size_t nfloats) {
        int n4 = (int)(nfloats / 4);
        int blocks = (n4 + 255) / 256;
        if (blocks > 4096) blocks = 4096;
        fill_zero<<<blocks, 256, 0, stream>>>((float*)p, n4);
    };

    // ---- CSR build ----
    zero(deg_i, 2 * (size_t)N);  // deg_i + cursor
    deg_count<<<(E + 255) / 256, 256, 0, stream>>>(dst, deg_i, E);
    scan_kernel<<<1, 1024, 0, stream>>>(deg_i, rowptr, N);
    inv_from_deg<<<(N + 255) / 256, 256, 0, stream>>>(deg_i, inv, N);
    csr_fill<<<(E + 255) / 256, 256, 0, stream>>>(src, dst, rowptr, cursor, csr, E);

    // ---- layer 1: 256 -> 256 ----
    gather_mean<64><<<(N + 3) / 4, 256, 0, stream>>>(x, rowptr, csr, inv, sbuf, N);
    sage_linear<256, 256><<<N / 16, 256, 0, stream>>>(sbuf, x, w1l, b1l, w1r, h1);
    zero(sums, 512);
    col_stats<256><<<256, 256, 0, stream>>>(h1, sums, sumsq, N);
    bn_finalize<256><<<1, 256, 0, stream>>>(sums, sumsq, g1, be1, scale, shift, N);
    bn_relu<256><<<2048, 256, 0, stream>>>(h1, scale, shift, N * 256 / 4);

    // ---- layer 2: 256 -> 128 ----
    gather_mean<64><<<(N + 3) / 4, 256, 0, stream>>>(h1, rowptr, csr, inv, sbuf, N);
    sage_linear<256, 128><<<N / 16, 256, 0, stream>>>(sbuf, h1, w2l, b2l, w2r, h2);
    zero(sums, 512);
    col_stats<128><<<256, 256, 0, stream>>>(h2, sums, sumsq, N);
    bn_finalize<128><<<1, 128, 0, stream>>>(sums, sumsq, g2, be2, scale, shift, N);
    bn_relu<128><<<2048, 256, 0, stream>>>(h2, scale, shift, N * 128 / 4);

    // ---- layer 3: 128 -> 64 ----
    gather_mean<32><<<(N + 7) / 8, 256, 0, stream>>>(h2, rowptr, csr, inv, sbuf, N);
    sage_linear<128, 64><<<N / 16, 256, 0, stream>>>(sbuf, h2, w3l, b3l, w3r, h3);
    zero(sums, 512);
    col_stats<64><<<256, 256, 0, stream>>>(h3, sums, sumsq, N);
    bn_finalize<64><<<1, 64, 0, stream>>>(sums, sumsq, g3, be3, scale, shift, N);
    bn_relu<64><<<2048, 256, 0, stream>>>(h3, scale, shift, N * 64 / 4);

    // ---- head ----
    head_kernel<<<(N + 255) / 256, 256, 0, stream>>>(h3, wh, bh, out, N);
}

// Round 3
// 487.308 us; speedup vs baseline: 15.2356x; 2.3812x over previous
//
#include <hip/hip_runtime.h>
#include <cstddef>
#include <cstdint>

#define N_NODES 50000
#define N_EDGES 800000
#define NP 50048   // 391 * 128, padded row count
static constexpr float BN_EPS = 1e-5f;

typedef unsigned short u16;
typedef short bf16x8 __attribute__((ext_vector_type(8)));
typedef float f32x4 __attribute__((ext_vector_type(4)));

// ---------------- helpers ----------------
__device__ inline u16 f2bf(float f) {
    union { float f; unsigned u; } v; v.f = f;
    unsigned r = v.u + 0x7fffu + ((v.u >> 16) & 1u);
    return (u16)(r >> 16);
}
__device__ inline unsigned pack2(float a, float b) {
    return (unsigned)f2bf(a) | ((unsigned)f2bf(b) << 16);
}
__device__ inline void addbf2(unsigned u, float& lo, float& hi) {
    union { unsigned u; float f; } t;
    t.u = u << 16; lo += t.f;
    t.u = u & 0xFFFF0000u; hi += t.f;
}
__device__ inline void bf2(unsigned u, float& lo, float& hi) {
    union { unsigned u; float f; } t;
    t.u = u << 16; lo = t.f;
    t.u = u & 0xFFFF0000u; hi = t.f;
}

// ---------------- utility: zero fill ----------------
__global__ void fill_zero(float* __restrict__ p, int n4) {
    float4* p4 = (float4*)p;
    for (int i = blockIdx.x * blockDim.x + threadIdx.x; i < n4; i += gridDim.x * blockDim.x)
        p4[i] = make_float4(0.f, 0.f, 0.f, 0.f);
}

// ---------------- fp32 -> bf16 convert ----------------
__global__ __launch_bounds__(256) void f32_to_bf16(const float* __restrict__ in,
                                                   u16* __restrict__ out, int n8) {
    const float4* in4 = (const float4*)in;
    uint4* out4 = (uint4*)out;
    for (int i = blockIdx.x * blockDim.x + threadIdx.x; i < n8; i += gridDim.x * blockDim.x) {
        float4 a = in4[2 * i], b = in4[2 * i + 1];
        uint4 u;
        u.x = pack2(a.x, a.y); u.y = pack2(a.z, a.w);
        u.z = pack2(b.x, b.y); u.w = pack2(b.z, b.w);
        out4[i] = u;
    }
}

// ---------------- CSR build ----------------
__global__ void deg_count(const int* __restrict__ dst, int* __restrict__ deg, int E) {
    int i = blockIdx.x * blockDim.x + threadIdx.x;
    if (i < E) atomicAdd(&deg[dst[i]], 1);
}

__global__ __launch_bounds__(1024) void scan_kernel(const int* __restrict__ deg,
                                                    int* __restrict__ rowptr, int n) {
    __shared__ int s[1024];
    const int t = threadIdx.x;
    const int CH = (n + 1023) / 1024;
    const int b = t * CH;
    const int e = min(b + CH, n);
    int sum = 0;
    for (int i = b; i < e; ++i) sum += deg[i];
    s[t] = sum;
    __syncthreads();
    for (int off = 1; off < 1024; off <<= 1) {
        int v = (t >= off) ? s[t - off] : 0;
        __syncthreads();
        s[t] += v;
        __syncthreads();
    }
    int base = (t == 0) ? 0 : s[t - 1];
    for (int i = b; i < e; ++i) { rowptr[i] = base; base += deg[i]; }
    if (t == 1023) rowptr[n] = base;
}

__global__ void inv_from_deg(const int* __restrict__ deg, float* __restrict__ inv, int n) {
    int i = blockIdx.x * blockDim.x + threadIdx.x;
    if (i < n) inv[i] = 1.0f / fmaxf((float)deg[i], 1.0f);
}

__global__ void csr_fill(const int* __restrict__ src, const int* __restrict__ dst,
                         const int* __restrict__ rowptr, int* __restrict__ cursor,
                         int* __restrict__ csr, int E) {
    int e = blockIdx.x * blockDim.x + threadIdx.x;
    if (e >= E) return;
    int d = dst[e];
    int p = atomicAdd(&cursor[d], 1);
    csr[rowptr[d] + p] = src[e];
}

// ---------------- gather-mean (bf16 in, bf16 out, fp32 accumulate) ----------------
template <int KH>
__global__ __launch_bounds__(256) void gather_mean_bf16(const u16* __restrict__ F,
                                                        const int* __restrict__ rowptr,
                                                        const int* __restrict__ csr,
                                                        const float* __restrict__ inv,
                                                        u16* __restrict__ Sout, int N) {
    constexpr int CG = KH / 8;       // threads per node (16B chunks)
    constexpr int NPB = 256 / CG;
    const int c = threadIdx.x % CG;
    const int node = blockIdx.x * NPB + threadIdx.x / CG;
    if (node >= N) return;
    const uint4* F4 = (const uint4*)F;
    float a0 = 0, a1 = 0, a2 = 0, a3 = 0, a4 = 0, a5 = 0, a6 = 0, a7 = 0;
    const int beg = rowptr[node], end = rowptr[node + 1];
    int k = beg;
    for (; k + 1 < end; k += 2) {
        uint4 va = F4[(size_t)csr[k] * CG + c];
        uint4 vb = F4[(size_t)csr[k + 1] * CG + c];
        addbf2(va.x, a0, a1); addbf2(va.y, a2, a3);
        addbf2(va.z, a4, a5); addbf2(va.w, a6, a7);
        addbf2(vb.x, a0, a1); addbf2(vb.y, a2, a3);
        addbf2(vb.z, a4, a5); addbf2(vb.w, a6, a7);
    }
    if (k < end) {
        uint4 va = F4[(size_t)csr[k] * CG + c];
        addbf2(va.x, a0, a1); addbf2(va.y, a2, a3);
        addbf2(va.z, a4, a5); addbf2(va.w, a6, a7);
    }
    const float w = inv[node];
    uint4 u;
    u.x = pack2(a0 * w, a1 * w); u.y = pack2(a2 * w, a3 * w);
    u.z = pack2(a4 * w, a5 * w); u.w = pack2(a6 * w, a7 * w);
    ((uint4*)Sout)[(size_t)node * CG + c] = u;
}

// ---------------- weight prep: WT[n][k] = bf16(concat(Wl,Wr)^T) ----------------
template <int KH, int NOUT>
__global__ __launch_bounds__(256) void wt_build(const float* __restrict__ Wl,
                                                const float* __restrict__ Wr,
                                                u16* __restrict__ WT) {
    constexpr int K = 2 * KH;
    int idx = blockIdx.x * 256 + threadIdx.x;
    if (idx >= NOUT * K) return;
    int n = idx / K, k = idx % K;
    float v = (k < KH) ? Wl[(size_t)k * NOUT + n] : Wr[(size_t)(k - KH) * NOUT + n];
    WT[idx] = f2bf(v);
}

// ---------------- MFMA GEMM: H = [S|X] @ W + b, fused BN-stat accumulation ----------------
// 128x64 tile per block, 4 waves (2x2), BK=32, double-buffered global_load_lds.
template <int KH, int K, int NOUT>
__global__ __launch_bounds__(256) void sage_gemm(const u16* __restrict__ S,
                                                 const u16* __restrict__ X,
                                                 const u16* __restrict__ WT,
                                                 const float* __restrict__ BL,
                                                 u16* __restrict__ Hb,
                                                 float* __restrict__ sums,
                                                 float* __restrict__ sumsq, int M) {
    constexpr int NK = K / 32;
    __shared__ __align__(16) u16 lds[2][6144];  // A: [0,4096) = 128x32, B: [4096,6144) = 64x32
    const int t = threadIdx.x;
    const int wid = t >> 6, lane = t & 63;
    const int row0 = blockIdx.x * 128;
    const int n0 = blockIdx.y * 64;
    const int wm = wid >> 1, wn = wid & 1;
    const int fr = lane & 15, fc = lane >> 4;

    auto stage = [&](int buf, int ks) {
        const int k0 = ks * 32;
        const u16* srcA;
        int kb;
        if (k0 < KH) { srcA = S; kb = k0; } else { srcA = X; kb = k0 - KH; }
#pragma unroll
        for (int jj = 0; jj < 2; ++jj) {
            int j = wid + jj * 4;
            const u16* g = srcA + (size_t)(row0 + j * 16 + (lane >> 2)) * KH + kb + (lane & 3) * 8;
            __builtin_amdgcn_global_load_lds(
                (const __attribute__((address_space(1))) void*)g,
                (__attribute__((address_space(3))) void*)&lds[buf][j * 512], 16, 0, 0);
        }
        const u16* gb = WT + (size_t)(n0 + wid * 16 + (lane >> 2)) * K + k0 + (lane & 3) * 8;
        __builtin_amdgcn_global_load_lds(
            (const __attribute__((address_space(1))) void*)gb,
            (__attribute__((address_space(3))) void*)&lds[buf][4096 + wid * 512], 16, 0, 0);
    };

    f32x4 acc[4][2] = {};

    stage(0, 0);
    for (int ks = 0; ks < NK; ++ks) {
        __syncthreads();   // drains vmcnt -> buffer ks&1 ready; all waves done reading (ks+1)&1
        if (ks + 1 < NK) stage((ks + 1) & 1, ks + 1);
        const u16* A = &lds[ks & 1][0];
        const u16* B = &lds[ks & 1][4096];
        bf16x8 a[4], b[2];
#pragma unroll
        for (int fm = 0; fm < 4; ++fm)
            a[fm] = *(const bf16x8*)&A[(wm * 64 + fm * 16 + fr) * 32 + fc * 8];
#pragma unroll
        for (int fn = 0; fn < 2; ++fn)
            b[fn] = *(const bf16x8*)&B[(wn * 32 + fn * 16 + fr) * 32 + fc * 8];
#pragma unroll
        for (int fm = 0; fm < 4; ++fm)
#pragma unroll
            for (int fn = 0; fn < 2; ++fn)
                acc[fm][fn] = __builtin_amdgcn_mfma_f32_16x16x32_bf16(a[fm], b[fn], acc[fm][fn], 0, 0, 0);
    }

    // epilogue: h = acc + bias; bf16 store; column sums/sumsq (valid rows only)
    const int colbase = n0 + wn * 32;
    const float bias0 = BL[colbase + fr];
    const float bias1 = BL[colbase + 16 + fr];
    float s0 = 0, ss0 = 0, s1 = 0, ss1 = 0;
#pragma unroll
    for (int fm = 0; fm < 4; ++fm) {
#pragma unroll
        for (int q = 0; q < 4; ++q) {
            int r = row0 + wm * 64 + fm * 16 + fc * 4 + q;
            float h0 = acc[fm][0][q] + bias0;
            float h1 = acc[fm][1][q] + bias1;
            if (r < M) {
                Hb[(size_t)r * NOUT + colbase + fr] = f2bf(h0);
                Hb[(size_t)r * NOUT + colbase + 16 + fr] = f2bf(h1);
                s0 += h0; ss0 += h0 * h0;
                s1 += h1; ss1 += h1 * h1;
            }
        }
    }
    // reduce over fc (lane bits 4,5): lanes with same fr sum their row groups
    s0 += __shfl_xor(s0, 16); s0 += __shfl_xor(s0, 32);
    ss0 += __shfl_xor(ss0, 16); ss0 += __shfl_xor(ss0, 32);
    s1 += __shfl_xor(s1, 16); s1 += __shfl_xor(s1, 32);
    ss1 += __shfl_xor(ss1, 16); ss1 += __shfl_xor(ss1, 32);
    if (fc == 0) {
        atomicAdd(&sums[colbase + fr], s0);
        atomicAdd(&sumsq[colbase + fr], ss0);
        atomicAdd(&sums[colbase + 16 + fr], s1);
        atomicAdd(&sumsq[colbase + 16 + fr], ss1);
    }
}

// ---------------- BN finalize ----------------
template <int M>
__global__ void bn_finalize(const float* __restrict__ sums, const float* __restrict__ sumsq,
                            const float* __restrict__ g, const float* __restrict__ beta,
                            float* __restrict__ scale, float* __restrict__ shift, int nrows) {
    int j = threadIdx.x;
    if (j >= M) return;
    float mean = sums[j] / nrows;
    float var = fmaxf(sumsq[j] / nrows - mean * mean, 0.f);
    float sc = g[j] * rsqrtf(var + BN_EPS);
    scale[j] = sc;
    shift[j] = beta[j] - mean * sc;
}

// ---------------- BN apply + ReLU (bf16 -> bf16) ----------------
template <int M>
__global__ __launch_bounds__(256) void bn_relu_bf16(const u16* __restrict__ Hb,
                                                    const float* __restrict__ scale,
                                                    const float* __restrict__ shift,
                                                    u16* __restrict__ Ob, int n8) {
    const uint4* H4 = (const uint4*)Hb;
    uint4* O4 = (uint4*)Ob;
    const float4* sc4 = (const float4*)scale;
    const float4* sh4 = (const float4*)shift;
    for (int i = blockIdx.x * blockDim.x + threadIdx.x; i < n8; i += gridDim.x * blockDim.x) {
        int jg = i % (M / 8);
        uint4 v = H4[i];
        float4 s0 = sc4[jg * 2], s1 = sc4[jg * 2 + 1];
        float4 b0 = sh4[jg * 2], b1 = sh4[jg * 2 + 1];
        float x0, x1, x2, x3, x4, x5, x6, x7;
        bf2(v.x, x0, x1); bf2(v.y, x2, x3); bf2(v.z, x4, x5); bf2(v.w, x6, x7);
        x0 = fmaxf(fmaf(x0, s0.x, b0.x), 0.f);
        x1 = fmaxf(fmaf(x1, s0.y, b0.y), 0.f);
        x2 = fmaxf(fmaf(x2, s0.z, b0.z), 0.f);
        x3 = fmaxf(fmaf(x3, s0.w, b0.w), 0.f);
        x4 = fmaxf(fmaf(x4, s1.x, b1.x), 0.f);
        x5 = fmaxf(fmaf(x5, s1.y, b1.y), 0.f);
        x6 = fmaxf(fmaf(x6, s1.z, b1.z), 0.f);
        x7 = fmaxf(fmaf(x7, s1.w, b1.w), 0.f);
        uint4 u;
        u.x = pack2(x0, x1); u.y = pack2(x2, x3);
        u.z = pack2(x4, x5); u.w = pack2(x6, x7);
        O4[i] = u;
    }
}

// ---------------- head: out = H3 @ wh + bh ----------------
__global__ __launch_bounds__(256) void head_bf16(const u16* __restrict__ H3,
                                                 const float* __restrict__ wh,
                                                 const float* __restrict__ bh,
                                                 float* __restrict__ out, int n) {
    int i = blockIdx.x * blockDim.x + threadIdx.x;
    if (i >= n) return;
    const uint4* h4 = (const uint4*)(H3 + (size_t)i * 64);
    float acc = bh[0];
#pragma unroll
    for (int c = 0; c < 4; ++c) {
        uint4 v = h4[c];
        float x0, x1, x2, x3, x4, x5, x6, x7;
        bf2(v.x, x0, x1); bf2(v.y, x2, x3); bf2(v.z, x4, x5); bf2(v.w, x6, x7);
        const float* w = wh + c * 16;
        acc += x0 * w[0] + x1 * w[1] + x2 * w[2] + x3 * w[3] +
               x4 * w[4] + x5 * w[5] + x6 * w[6] + x7 * w[7];
    }
    // wait: 64 = 4 chunks * 16? no: 4 uint4 = 16 u32 = 32 bf16... need 8 chunks of 8
    out[i] = acc;
}

// corrected head (64 feats = 8 uint4? no: 64 bf16 = 32 u32 = 8 uint4? 64*2B=128B=8x16B)
__global__ __launch_bounds__(256) void head_bf16_v2(const u16* __restrict__ H3,
                                                    const float* __restrict__ wh,
                                                    const float* __restrict__ bh,
                                                    float* __restrict__ out, int n) {
    int i = blockIdx.x * blockDim.x + threadIdx.x;
    if (i >= n) return;
    const uint4* h4 = (const uint4*)(H3 + (size_t)i * 64);
    float acc = bh[0];
#pragma unroll
    for (int c = 0; c < 8; ++c) {
        uint4 v = h4[c];
        float x0, x1, x2, x3, x4, x5, x6, x7;
        bf2(v.x, x0, x1); bf2(v.y, x2, x3); bf2(v.z, x4, x5); bf2(v.w, x6, x7);
        const float* w = wh + c * 8;
        acc += x0 * w[0] + x1 * w[1] + x2 * w[2] + x3 * w[3] +
               x4 * w[4] + x5 * w[5] + x6 * w[6] + x7 * w[7];
    }
    out[i] = acc;
}

// ---------------- launch ----------------
extern "C" void kernel_launch(void* const* d_in, const int* in_sizes, int n_in,
                              void* d_out, int out_size, void* d_ws, size_t ws_size,
                              hipStream_t stream) {
    const int N = N_NODES, E = N_EDGES;
    const float* x   = (const float*)d_in[0];
    const int*   ei  = (const int*)d_in[1];
    const int*   src = ei;
    const int*   dst = ei + E;
    const float* w1l = (const float*)d_in[2];
    const float* b1l = (const float*)d_in[3];
    const float* w1r = (const float*)d_in[4];
    const float* g1  = (const float*)d_in[5];
    const float* be1 = (const float*)d_in[6];
    const float* w2l = (const float*)d_in[7];
    const float* b2l = (const float*)d_in[8];
    const float* w2r = (const float*)d_in[9];
    const float* g2  = (const float*)d_in[10];
    const float* be2 = (const float*)d_in[11];
    const float* w3l = (const float*)d_in[12];
    const float* b3l = (const float*)d_in[13];
    const float* w3r = (const float*)d_in[14];
    const float* g3  = (const float*)d_in[15];
    const float* be3 = (const float*)d_in[16];
    const float* wh  = (const float*)d_in[17];
    const float* bh  = (const float*)d_in[18];
    float* out = (float*)d_out;

    // ---- workspace layout (256B-aligned regions) ----
    char* base = (char*)d_ws;
    size_t off = 0;
    auto alloc = [&](size_t bytes) -> void* {
        void* r = base + off;
        off += (bytes + 255) & ~(size_t)255;
        return r;
    };
    int*   rowptr = (int*)alloc((N + 8) * sizeof(int));
    int*   csr    = (int*)alloc((size_t)E * sizeof(int));
    int*   deg_i  = (int*)alloc(N * sizeof(int));
    int*   cursor = (int*)alloc(N * sizeof(int));
    float* inv    = (float*)alloc(N * sizeof(float));
    u16*   xb     = (u16*)alloc((size_t)NP * 256 * 2);
    u16*   sB     = (u16*)alloc((size_t)NP * 256 * 2);
    u16*   h1b    = (u16*)alloc((size_t)NP * 256 * 2);
    u16*   h2b    = (u16*)alloc((size_t)NP * 128 * 2);
    u16*   h3b    = (u16*)alloc((size_t)NP * 64 * 2);
    u16*   hpre   = (u16*)alloc((size_t)NP * 256 * 2);
    u16*   wt     = (u16*)alloc((size_t)256 * 512 * 2);
    float* stats  = (float*)alloc(1024 * sizeof(float));
    float* sums = stats, *sumsq = stats + 256, *scale = stats + 512, *shift = stats + 768;

    auto zero = [&](void* p, size_t nfloats) {
        int n4 = (int)(nfloats / 4);
        int blocks = (n4 + 255) / 256;
        if (blocks > 2048) blocks = 2048;
        fill_zero<<<blocks, 256, 0, stream>>>((float*)p, n4);
    };

    // ---- prep: x -> bf16 ----
    f32_to_bf16<<<2048, 256, 0, stream>>>(x, xb, N * 256 / 8);

    // ---- CSR build ----
    zero(deg_i, N);
    zero(cursor, N);
    deg_count<<<(E + 255) / 256, 256, 0, stream>>>(dst, deg_i, E);
    scan_kernel<<<1, 1024, 0, stream>>>(deg_i, rowptr, N);
    inv_from_deg<<<(N + 255) / 256, 256, 0, stream>>>(deg_i, inv, N);
    csr_fill<<<(E + 255) / 256, 256, 0, stream>>>(src, dst, rowptr, cursor, csr, E);

    const int MB = NP / 128;  // 391

    // ---- layer 1: K=512 (256|256) -> 256 ----
    gather_mean_bf16<256><<<(N * 32 + 255) / 256, 256, 0, stream>>>(xb, rowptr, csr, inv, sB, N);
    wt_build<256, 256><<<(256 * 512 + 255) / 256, 256, 0, stream>>>(w1l, w1r, wt);
    zero(sums, 512);
    sage_gemm<256, 512, 256><<<dim3(MB, 4), 256, 0, stream>>>(sB, xb, wt, b1l, hpre, sums, sumsq, N);
    bn_finalize<256><<<1, 256, 0, stream>>>(sums, sumsq, g1, be1, scale, shift, N);
    bn_relu_bf16<256><<<2048, 256, 0, stream>>>(hpre, scale, shift, h1b, N * 256 / 8);

    // ---- layer 2: K=512 (256|256) -> 128 ----
    gather_mean_bf16<256><<<(N * 32 + 255) / 256, 256, 0, stream>>>(h1b, rowptr, csr, inv, sB, N);
    wt_build<256, 128><<<(128 * 512 + 255) / 256, 256, 0, stream>>>(w2l, w2r, wt);
    zero(sums, 512);
    sage_gemm<256, 512, 128><<<dim3(MB, 2), 256, 0, stream>>>(sB, h1b, wt, b2l, hpre, sums, sumsq, N);
    bn_finalize<128><<<1, 128, 0, stream>>>(sums, sumsq, g2, be2, scale, shift, N);
    bn_relu_bf16<128><<<2048, 256, 0, stream>>>(hpre, scale, shift, h2b, N * 128 / 8);

    // ---- layer 3: K=256 (128|128) -> 64 ----
    gather_mean_bf16<128><<<(N * 16 + 255) / 256, 256, 0, stream>>>(h2b, rowptr, csr, inv, sB, N);
    wt_build<128, 64><<<(64 * 256 + 255) / 256, 256, 0, stream>>>(w3l, w3r, wt);
    zero(sums, 512);
    sage_gemm<128, 256, 64><<<dim3(MB, 1), 256, 0, stream>>>(sB, h2b, wt, b3l, hpre, sums, sumsq, N);
    bn_finalize<64><<<1, 64, 0, stream>>>(sums, sumsq, g3, be3, scale, shift, N);
    bn_relu_bf16<64><<<2048, 256, 0, stream>>>(hpre, scale, shift, h3b, N * 64 / 8);

    // ---- head ----
    head_bf16_v2<<<(N + 255) / 256, 256, 0, stream>>>(h3b, wh, bh, out, N);
}

// Round 4
// 413.990 us; speedup vs baseline: 17.9338x; 1.1771x over previous
//
#include <hip/hip_runtime.h>
#include <cstddef>
#include <cstdint>

#define N_NODES 50000
#define N_EDGES 800000
#define NP 50048   // 391 * 128, padded row count
static constexpr float BN_EPS = 1e-5f;

typedef unsigned short u16;
typedef short bf16x8 __attribute__((ext_vector_type(8)));
typedef float f32x4 __attribute__((ext_vector_type(4)));

// ---------------- helpers ----------------
__device__ inline u16 f2bf(float f) {
    union { float f; unsigned u; } v; v.f = f;
    unsigned r = v.u + 0x7fffu + ((v.u >> 16) & 1u);
    return (u16)(r >> 16);
}
__device__ inline unsigned pack2(float a, float b) {
    return (unsigned)f2bf(a) | ((unsigned)f2bf(b) << 16);
}
__device__ inline void addbf2(unsigned u, float& lo, float& hi) {
    union { unsigned u; float f; } t;
    t.u = u << 16; lo += t.f;
    t.u = u & 0xFFFF0000u; hi += t.f;
}
__device__ inline void bf2(unsigned u, float& lo, float& hi) {
    union { unsigned u; float f; } t;
    t.u = u << 16; lo = t.f;
    t.u = u & 0xFFFF0000u; hi = t.f;
}

// ---------------- utility: zero fill ----------------
__global__ void fill_zero(float* __restrict__ p, int n4) {
    float4* p4 = (float4*)p;
    for (int i = blockIdx.x * blockDim.x + threadIdx.x; i < n4; i += gridDim.x * blockDim.x)
        p4[i] = make_float4(0.f, 0.f, 0.f, 0.f);
}

// ---------------- fp32 -> bf16 convert ----------------
__global__ __launch_bounds__(256) void f32_to_bf16(const float* __restrict__ in,
                                                   u16* __restrict__ out, int n8) {
    const float4* in4 = (const float4*)in;
    uint4* out4 = (uint4*)out;
    for (int i = blockIdx.x * blockDim.x + threadIdx.x; i < n8; i += gridDim.x * blockDim.x) {
        float4 a = in4[2 * i], b = in4[2 * i + 1];
        uint4 u;
        u.x = pack2(a.x, a.y); u.y = pack2(a.z, a.w);
        u.z = pack2(b.x, b.y); u.w = pack2(b.z, b.w);
        out4[i] = u;
    }
}

// ---------------- CSR build ----------------
__global__ void deg_count(const int* __restrict__ dst, int* __restrict__ deg, int E) {
    int i = blockIdx.x * blockDim.x + threadIdx.x;
    if (i < E) atomicAdd(&deg[dst[i]], 1);
}

// 3-phase parallel exclusive scan over deg[0..n) -> rowptr[0..n]
__global__ __launch_bounds__(256) void scan_phase1(const int* __restrict__ deg,
                                                   int* __restrict__ rowptr,
                                                   int* __restrict__ blocksum, int n) {
    __shared__ int s[256];
    const int t = threadIdx.x;
    const int i = blockIdx.x * 256 + t;
    int d = (i < n) ? deg[i] : 0;
    s[t] = d;
    __syncthreads();
    for (int off = 1; off < 256; off <<= 1) {
        int v = (t >= off) ? s[t - off] : 0;
        __syncthreads();
        s[t] += v;
        __syncthreads();
    }
    if (i < n) rowptr[i] = s[t] - d;      // intra-block exclusive
    if (t == 255) blocksum[blockIdx.x] = s[t];
}

__global__ __launch_bounds__(256) void scan_phase2(int* __restrict__ blocksum,
                                                   int* __restrict__ rowptr, int nb, int n) {
    __shared__ int s[256];
    const int t = threadIdx.x;
    int d = (t < nb) ? blocksum[t] : 0;
    s[t] = d;
    __syncthreads();
    for (int off = 1; off < 256; off <<= 1) {
        int v = (t >= off) ? s[t - off] : 0;
        __syncthreads();
        s[t] += v;
        __syncthreads();
    }
    if (t < nb) blocksum[t] = s[t] - d;   // exclusive block offsets
    if (t == 255) rowptr[n] = s[t];       // total = E
}

__global__ __launch_bounds__(256) void scan_phase3(int* __restrict__ rowptr,
                                                   const int* __restrict__ blocksum,
                                                   const int* __restrict__ deg,
                                                   float* __restrict__ inv, int n) {
    int i = blockIdx.x * 256 + threadIdx.x;
    if (i >= n) return;
    rowptr[i] += blocksum[i >> 8];
    inv[i] = 1.0f / fmaxf((float)deg[i], 1.0f);
}

__global__ void csr_fill(const int* __restrict__ src, const int* __restrict__ dst,
                         const int* __restrict__ rowptr, int* __restrict__ cursor,
                         int* __restrict__ csr, int E) {
    int e = blockIdx.x * blockDim.x + threadIdx.x;
    if (e >= E) return;
    int d = dst[e];
    int p = atomicAdd(&cursor[d], 1);
    csr[rowptr[d] + p] = src[e];
}

// ---------------- gather-mean (bf16 in, bf16 out, fp32 accumulate) ----------------
template <int KH>
__global__ __launch_bounds__(256) void gather_mean_bf16(const u16* __restrict__ F,
                                                        const int* __restrict__ rowptr,
                                                        const int* __restrict__ csr,
                                                        const float* __restrict__ inv,
                                                        u16* __restrict__ Sout, int N) {
    constexpr int CG = KH / 8;       // threads per node (16B chunks)
    constexpr int NPB = 256 / CG;
    const int c = threadIdx.x % CG;
    const int node = blockIdx.x * NPB + threadIdx.x / CG;
    if (node >= N) return;
    const uint4* F4 = (const uint4*)F;
    float a0 = 0, a1 = 0, a2 = 0, a3 = 0, a4 = 0, a5 = 0, a6 = 0, a7 = 0;
    const int beg = rowptr[node], end = rowptr[node + 1];
    int k = beg;
    for (; k + 1 < end; k += 2) {
        uint4 va = F4[(size_t)csr[k] * CG + c];
        uint4 vb = F4[(size_t)csr[k + 1] * CG + c];
        addbf2(va.x, a0, a1); addbf2(va.y, a2, a3);
        addbf2(va.z, a4, a5); addbf2(va.w, a6, a7);
        addbf2(vb.x, a0, a1); addbf2(vb.y, a2, a3);
        addbf2(vb.z, a4, a5); addbf2(vb.w, a6, a7);
    }
    if (k < end) {
        uint4 va = F4[(size_t)csr[k] * CG + c];
        addbf2(va.x, a0, a1); addbf2(va.y, a2, a3);
        addbf2(va.z, a4, a5); addbf2(va.w, a6, a7);
    }
    const float w = inv[node];
    uint4 u;
    u.x = pack2(a0 * w, a1 * w); u.y = pack2(a2 * w, a3 * w);
    u.z = pack2(a4 * w, a5 * w); u.w = pack2(a6 * w, a7 * w);
    ((uint4*)Sout)[(size_t)node * CG + c] = u;
}

// ---------------- weight prep: WT[n][k] = bf16(concat(Wl,Wr)^T) ----------------
template <int KH, int NOUT>
__global__ __launch_bounds__(256) void wt_build(const float* __restrict__ Wl,
                                                const float* __restrict__ Wr,
                                                u16* __restrict__ WT) {
    constexpr int K = 2 * KH;
    int idx = blockIdx.x * 256 + threadIdx.x;
    if (idx >= NOUT * K) return;
    int n = idx / K, k = idx % K;
    float v = (k < KH) ? Wl[(size_t)k * NOUT + n] : Wr[(size_t)(k - KH) * NOUT + n];
    WT[idx] = f2bf(v);
}

// ---------------- MFMA GEMM: H = [S|X] @ W + b, fused BN-stat accumulation ----------------
// 128x64 tile per block, 4 waves (2x2), BK=32, double-buffered global_load_lds.
template <int KH, int K, int NOUT>
__global__ __launch_bounds__(256) void sage_gemm(const u16* __restrict__ S,
                                                 const u16* __restrict__ X,
                                                 const u16* __restrict__ WT,
                                                 const float* __restrict__ BL,
                                                 u16* __restrict__ Hb,
                                                 float* __restrict__ sums,
                                                 float* __restrict__ sumsq, int M) {
    constexpr int NK = K / 32;
    __shared__ __align__(16) u16 lds[2][6144];  // A: [0,4096) = 128x32, B: [4096,6144) = 64x32
    const int t = threadIdx.x;
    const int wid = t >> 6, lane = t & 63;
    const int row0 = blockIdx.x * 128;
    const int n0 = blockIdx.y * 64;
    const int wm = wid >> 1, wn = wid & 1;
    const int fr = lane & 15, fc = lane >> 4;

    auto stage = [&](int buf, int ks) {
        const int k0 = ks * 32;
        const u16* srcA;
        int kb;
        if (k0 < KH) { srcA = S; kb = k0; } else { srcA = X; kb = k0 - KH; }
#pragma unroll
        for (int jj = 0; jj < 2; ++jj) {
            int j = wid + jj * 4;
            const u16* g = srcA + (size_t)(row0 + j * 16 + (lane >> 2)) * KH + kb + (lane & 3) * 8;
            __builtin_amdgcn_global_load_lds(
                (const __attribute__((address_space(1))) void*)g,
                (__attribute__((address_space(3))) void*)&lds[buf][j * 512], 16, 0, 0);
        }
        const u16* gb = WT + (size_t)(n0 + wid * 16 + (lane >> 2)) * K + k0 + (lane & 3) * 8;
        __builtin_amdgcn_global_load_lds(
            (const __attribute__((address_space(1))) void*)gb,
            (__attribute__((address_space(3))) void*)&lds[buf][4096 + wid * 512], 16, 0, 0);
    };

    f32x4 acc[4][2] = {};

    stage(0, 0);
    for (int ks = 0; ks < NK; ++ks) {
        __syncthreads();   // drains vmcnt -> buffer ks&1 ready; all waves done reading (ks+1)&1
        if (ks + 1 < NK) stage((ks + 1) & 1, ks + 1);
        const u16* A = &lds[ks & 1][0];
        const u16* B = &lds[ks & 1][4096];
        bf16x8 a[4], b[2];
#pragma unroll
        for (int fm = 0; fm < 4; ++fm)
            a[fm] = *(const bf16x8*)&A[(wm * 64 + fm * 16 + fr) * 32 + fc * 8];
#pragma unroll
        for (int fn = 0; fn < 2; ++fn)
            b[fn] = *(const bf16x8*)&B[(wn * 32 + fn * 16 + fr) * 32 + fc * 8];
#pragma unroll
        for (int fm = 0; fm < 4; ++fm)
#pragma unroll
            for (int fn = 0; fn < 2; ++fn)
                acc[fm][fn] = __builtin_amdgcn_mfma_f32_16x16x32_bf16(a[fm], b[fn], acc[fm][fn], 0, 0, 0);
    }

    // epilogue: h = acc + bias; bf16 store; column sums/sumsq (valid rows only)
    const int colbase = n0 + wn * 32;
    const float bias0 = BL[colbase + fr];
    const float bias1 = BL[colbase + 16 + fr];
    float s0 = 0, ss0 = 0, s1 = 0, ss1 = 0;
#pragma unroll
    for (int fm = 0; fm < 4; ++fm) {
#pragma unroll
        for (int q = 0; q < 4; ++q) {
            int r = row0 + wm * 64 + fm * 16 + fc * 4 + q;
            float h0 = acc[fm][0][q] + bias0;
            float h1 = acc[fm][1][q] + bias1;
            if (r < M) {
                Hb[(size_t)r * NOUT + colbase + fr] = f2bf(h0);
                Hb[(size_t)r * NOUT + colbase + 16 + fr] = f2bf(h1);
                s0 += h0; ss0 += h0 * h0;
                s1 += h1; ss1 += h1 * h1;
            }
        }
    }
    // reduce over fc (lane bits 4,5): lanes with same fr sum their row groups
    s0 += __shfl_xor(s0, 16); s0 += __shfl_xor(s0, 32);
    ss0 += __shfl_xor(ss0, 16); ss0 += __shfl_xor(ss0, 32);
    s1 += __shfl_xor(s1, 16); s1 += __shfl_xor(s1, 32);
    ss1 += __shfl_xor(ss1, 16); ss1 += __shfl_xor(ss1, 32);
    if (fc == 0) {
        atomicAdd(&sums[colbase + fr], s0);
        atomicAdd(&sumsq[colbase + fr], ss0);
        atomicAdd(&sums[colbase + 16 + fr], s1);
        atomicAdd(&sumsq[colbase + 16 + fr], ss1);
    }
}

// ---------------- BN finalize ----------------
template <int M>
__global__ void bn_finalize(const float* __restrict__ sums, const float* __restrict__ sumsq,
                            const float* __restrict__ g, const float* __restrict__ beta,
                            float* __restrict__ scale, float* __restrict__ shift, int nrows) {
    int j = threadIdx.x;
    if (j >= M) return;
    float mean = sums[j] / nrows;
    float var = fmaxf(sumsq[j] / nrows - mean * mean, 0.f);
    float sc = g[j] * rsqrtf(var + BN_EPS);
    scale[j] = sc;
    shift[j] = beta[j] - mean * sc;
}

// ---------------- BN apply + ReLU (bf16 -> bf16) ----------------
template <int M>
__global__ __launch_bounds__(256) void bn_relu_bf16(const u16* __restrict__ Hb,
                                                    const float* __restrict__ scale,
                                                    const float* __restrict__ shift,
                                                    u16* __restrict__ Ob, int n8) {
    const uint4* H4 = (const uint4*)Hb;
    uint4* O4 = (uint4*)Ob;
    const float4* sc4 = (const float4*)scale;
    const float4* sh4 = (const float4*)shift;
    for (int i = blockIdx.x * blockDim.x + threadIdx.x; i < n8; i += gridDim.x * blockDim.x) {
        int jg = i % (M / 8);
        uint4 v = H4[i];
        float4 s0 = sc4[jg * 2], s1 = sc4[jg * 2 + 1];
        float4 b0 = sh4[jg * 2], b1 = sh4[jg * 2 + 1];
        float x0, x1, x2, x3, x4, x5, x6, x7;
        bf2(v.x, x0, x1); bf2(v.y, x2, x3); bf2(v.z, x4, x5); bf2(v.w, x6, x7);
        x0 = fmaxf(fmaf(x0, s0.x, b0.x), 0.f);
        x1 = fmaxf(fmaf(x1, s0.y, b0.y), 0.f);
        x2 = fmaxf(fmaf(x2, s0.z, b0.z), 0.f);
        x3 = fmaxf(fmaf(x3, s0.w, b0.w), 0.f);
        x4 = fmaxf(fmaf(x4, s1.x, b1.x), 0.f);
        x5 = fmaxf(fmaf(x5, s1.y, b1.y), 0.f);
        x6 = fmaxf(fmaf(x6, s1.z, b1.z), 0.f);
        x7 = fmaxf(fmaf(x7, s1.w, b1.w), 0.f);
        uint4 u;
        u.x = pack2(x0, x1); u.y = pack2(x2, x3);
        u.z = pack2(x4, x5); u.w = pack2(x6, x7);
        O4[i] = u;
    }
}

// ---------------- head: out = H3 @ wh + bh ----------------
__global__ __launch_bounds__(256) void head_bf16_v2(const u16* __restrict__ H3,
                                                    const float* __restrict__ wh,
                                                    const float* __restrict__ bh,
                                                    float* __restrict__ out, int n) {
    int i = blockIdx.x * blockDim.x + threadIdx.x;
    if (i >= n) return;
    const uint4* h4 = (const uint4*)(H3 + (size_t)i * 64);
    float acc = bh[0];
#pragma unroll
    for (int c = 0; c < 8; ++c) {
        uint4 v = h4[c];
        float x0, x1, x2, x3, x4, x5, x6, x7;
        bf2(v.x, x0, x1); bf2(v.y, x2, x3); bf2(v.z, x4, x5); bf2(v.w, x6, x7);
        const float* w = wh + c * 8;
        acc += x0 * w[0] + x1 * w[1] + x2 * w[2] + x3 * w[3] +
               x4 * w[4] + x5 * w[5] + x6 * w[6] + x7 * w[7];
    }
    out[i] = acc;
}

// ---------------- launch ----------------
extern "C" void kernel_launch(void* const* d_in, const int* in_sizes, int n_in,
                              void* d_out, int out_size, void* d_ws, size_t ws_size,
                              hipStream_t stream) {
    const int N = N_NODES, E = N_EDGES;
    const float* x   = (const float*)d_in[0];
    const int*   ei  = (const int*)d_in[1];
    const int*   src = ei;
    const int*   dst = ei + E;
    const float* w1l = (const float*)d_in[2];
    const float* b1l = (const float*)d_in[3];
    const float* w1r = (const float*)d_in[4];
    const float* g1  = (const float*)d_in[5];
    const float* be1 = (const float*)d_in[6];
    const float* w2l = (const float*)d_in[7];
    const float* b2l = (const float*)d_in[8];
    const float* w2r = (const float*)d_in[9];
    const float* g2  = (const float*)d_in[10];
    const float* be2 = (const float*)d_in[11];
    const float* w3l = (const float*)d_in[12];
    const float* b3l = (const float*)d_in[13];
    const float* w3r = (const float*)d_in[14];
    const float* g3  = (const float*)d_in[15];
    const float* be3 = (const float*)d_in[16];
    const float* wh  = (const float*)d_in[17];
    const float* bh  = (const float*)d_in[18];
    float* out = (float*)d_out;

    // ---- workspace layout (256B-aligned regions) ----
    char* base = (char*)d_ws;
    size_t off = 0;
    auto alloc = [&](size_t bytes) -> void* {
        void* r = base + off;
        off += (bytes + 255) & ~(size_t)255;
        return r;
    };
    const int NB = (N + 255) / 256;  // 196 scan blocks
    int*   rowptr = (int*)alloc((N + 8) * sizeof(int));
    int*   csr    = (int*)alloc((size_t)E * sizeof(int));
    int*   ints2  = (int*)alloc(2 * (size_t)N * sizeof(int));  // deg_i | cursor
    int*   deg_i  = ints2;
    int*   cursor = ints2 + N;
    int*   bsum   = (int*)alloc(256 * sizeof(int));
    float* inv    = (float*)alloc(N * sizeof(float));
    u16*   xb     = (u16*)alloc((size_t)NP * 256 * 2);
    u16*   sB     = (u16*)alloc((size_t)NP * 256 * 2);
    u16*   h1b    = (u16*)alloc((size_t)NP * 256 * 2);
    u16*   h2b    = (u16*)alloc((size_t)NP * 128 * 2);
    u16*   h3b    = (u16*)alloc((size_t)NP * 64 * 2);
    u16*   hpre   = (u16*)alloc((size_t)NP * 256 * 2);
    u16*   wt     = (u16*)alloc((size_t)256 * 512 * 2);
    float* stats  = (float*)alloc(1024 * sizeof(float));
    float* sums = stats, *sumsq = stats + 256, *scale = stats + 512, *shift = stats + 768;

    auto zero = [&](void* p, size_t nfloats) {
        int n4 = (int)(nfloats / 4);
        int blocks = (n4 + 255) / 256;
        if (blocks > 2048) blocks = 2048;
        fill_zero<<<blocks, 256, 0, stream>>>((float*)p, n4);
    };

    // ---- prep: x -> bf16 ----
    f32_to_bf16<<<2048, 256, 0, stream>>>(x, xb, N * 256 / 8);

    // ---- CSR build (3-phase parallel scan) ----
    zero(ints2, 2 * (size_t)N);  // deg_i + cursor in one dispatch
    deg_count<<<(E + 255) / 256, 256, 0, stream>>>(dst, deg_i, E);
    scan_phase1<<<NB, 256, 0, stream>>>(deg_i, rowptr, bsum, N);
    scan_phase2<<<1, 256, 0, stream>>>(bsum, rowptr, NB, N);
    scan_phase3<<<NB, 256, 0, stream>>>(rowptr, bsum, deg_i, inv, N);
    csr_fill<<<(E + 255) / 256, 256, 0, stream>>>(src, dst, rowptr, cursor, csr, E);

    const int MB = NP / 128;  // 391

    // ---- layer 1: K=512 (256|256) -> 256 ----
    gather_mean_bf16<256><<<(N * 32 + 255) / 256, 256, 0, stream>>>(xb, rowptr, csr, inv, sB, N);
    wt_build<256, 256><<<(256 * 512 + 255) / 256, 256, 0, stream>>>(w1l, w1r, wt);
    zero(sums, 512);
    sage_gemm<256, 512, 256><<<dim3(MB, 4), 256, 0, stream>>>(sB, xb, wt, b1l, hpre, sums, sumsq, N);
    bn_finalize<256><<<1, 256, 0, stream>>>(sums, sumsq, g1, be1, scale, shift, N);
    bn_relu_bf16<256><<<2048, 256, 0, stream>>>(hpre, scale, shift, h1b, N * 256 / 8);

    // ---- layer 2: K=512 (256|256) -> 128 ----
    gather_mean_bf16<256><<<(N * 32 + 255) / 256, 256, 0, stream>>>(h1b, rowptr, csr, inv, sB, N);
    wt_build<256, 128><<<(128 * 512 + 255) / 256, 256, 0, stream>>>(w2l, w2r, wt);
    zero(sums, 512);
    sage_gemm<256, 512, 128><<<dim3(MB, 2), 256, 0, stream>>>(sB, h1b, wt, b2l, hpre, sums, sumsq, N);
    bn_finalize<128><<<1, 128, 0, stream>>>(sums, sumsq, g2, be2, scale, shift, N);
    bn_relu_bf16<128><<<2048, 256, 0, stream>>>(hpre, scale, shift, h2b, N * 128 / 8);

    // ---- layer 3: K=256 (128|128) -> 64 ----
    gather_mean_bf16<128><<<(N * 16 + 255) / 256, 256, 0, stream>>>(h2b, rowptr, csr, inv, sB, N);
    wt_build<128, 64><<<(64 * 256 + 255) / 256, 256, 0, stream>>>(w3l, w3r, wt);
    zero(sums, 512);
    sage_gemm<128, 256, 64><<<dim3(MB, 1), 256, 0, stream>>>(sB, h2b, wt, b3l, hpre, sums, sumsq, N);
    bn_finalize<64><<<1, 64, 0, stream>>>(sums, sumsq, g3, be3, scale, shift, N);
    bn_relu_bf16<64><<<2048, 256, 0, stream>>>(hpre, scale, shift, h3b, N * 64 / 8);

    // ---- head ----
    head_bf16_v2<<<(N + 255) / 256, 256, 0, stream>>>(h3b, wh, bh, out, N);
}

// Round 5
// 376.290 us; speedup vs baseline: 19.7306x; 1.1002x over previous
//
#include <hip/hip_runtime.h>
#include <cstddef>
#include <cstdint>

#define N_NODES 50000
#define N_EDGES 800000
#define NP 50048   // 391 * 128, padded row count
static constexpr float BN_EPS = 1e-5f;

typedef unsigned short u16;
typedef short bf16x8 __attribute__((ext_vector_type(8)));
typedef float f32x4 __attribute__((ext_vector_type(4)));

// ---------------- helpers ----------------
__device__ inline u16 f2bf(float f) {
    union { float f; unsigned u; } v; v.f = f;
    unsigned r = v.u + 0x7fffu + ((v.u >> 16) & 1u);
    return (u16)(r >> 16);
}
__device__ inline unsigned pack2(float a, float b) {
    return (unsigned)f2bf(a) | ((unsigned)f2bf(b) << 16);
}
__device__ inline void addbf2(unsigned u, float& lo, float& hi) {
    union { unsigned u; float f; } t;
    t.u = u << 16; lo += t.f;
    t.u = u & 0xFFFF0000u; hi += t.f;
}
__device__ inline void bf2(unsigned u, float& lo, float& hi) {
    union { unsigned u; float f; } t;
    t.u = u << 16; lo = t.f;
    t.u = u & 0xFFFF0000u; hi = t.f;
}

// ---------------- utility: zero fill ----------------
__global__ void fill_zero(float* __restrict__ p, int n4) {
    float4* p4 = (float4*)p;
    for (int i = blockIdx.x * blockDim.x + threadIdx.x; i < n4; i += gridDim.x * blockDim.x)
        p4[i] = make_float4(0.f, 0.f, 0.f, 0.f);
}

// ---------------- fp32 -> bf16 convert ----------------
__global__ __launch_bounds__(256) void f32_to_bf16(const float* __restrict__ in,
                                                   u16* __restrict__ out, int n8) {
    const float4* in4 = (const float4*)in;
    uint4* out4 = (uint4*)out;
    for (int i = blockIdx.x * blockDim.x + threadIdx.x; i < n8; i += gridDim.x * blockDim.x) {
        float4 a = in4[2 * i], b = in4[2 * i + 1];
        uint4 u;
        u.x = pack2(a.x, a.y); u.y = pack2(a.z, a.w);
        u.z = pack2(b.x, b.y); u.w = pack2(b.z, b.w);
        out4[i] = u;
    }
}

// ---------------- CSR build ----------------
__global__ void deg_count(const int* __restrict__ dst, int* __restrict__ deg, int E) {
    int i = blockIdx.x * blockDim.x + threadIdx.x;
    if (i < E) atomicAdd(&deg[dst[i]], 1);
}

// 3-phase parallel exclusive scan over deg[0..n) -> rowptr[0..n]
__global__ __launch_bounds__(256) void scan_phase1(const int* __restrict__ deg,
                                                   int* __restrict__ rowptr,
                                                   int* __restrict__ blocksum, int n) {
    __shared__ int s[256];
    const int t = threadIdx.x;
    const int i = blockIdx.x * 256 + t;
    int d = (i < n) ? deg[i] : 0;
    s[t] = d;
    __syncthreads();
    for (int off = 1; off < 256; off <<= 1) {
        int v = (t >= off) ? s[t - off] : 0;
        __syncthreads();
        s[t] += v;
        __syncthreads();
    }
    if (i < n) rowptr[i] = s[t] - d;      // intra-block exclusive
    if (t == 255) blocksum[blockIdx.x] = s[t];
}

__global__ __launch_bounds__(256) void scan_phase2(int* __restrict__ blocksum,
                                                   int* __restrict__ rowptr, int nb, int n) {
    __shared__ int s[256];
    const int t = threadIdx.x;
    int d = (t < nb) ? blocksum[t] : 0;
    s[t] = d;
    __syncthreads();
    for (int off = 1; off < 256; off <<= 1) {
        int v = (t >= off) ? s[t - off] : 0;
        __syncthreads();
        s[t] += v;
        __syncthreads();
    }
    if (t < nb) blocksum[t] = s[t] - d;   // exclusive block offsets
    if (t == 255) rowptr[n] = s[t];       // total = E
}

__global__ __launch_bounds__(256) void scan_phase3(int* __restrict__ rowptr,
                                                   const int* __restrict__ blocksum,
                                                   const int* __restrict__ deg,
                                                   float* __restrict__ inv, int n) {
    int i = blockIdx.x * 256 + threadIdx.x;
    if (i >= n) return;
    rowptr[i] += blocksum[i >> 8];
    inv[i] = 1.0f / fmaxf((float)deg[i], 1.0f);
}

__global__ void csr_fill(const int* __restrict__ src, const int* __restrict__ dst,
                         const int* __restrict__ rowptr, int* __restrict__ cursor,
                         int* __restrict__ csr, int E) {
    int e = blockIdx.x * blockDim.x + threadIdx.x;
    if (e >= E) return;
    int d = dst[e];
    int p = atomicAdd(&cursor[d], 1);
    csr[rowptr[d] + p] = src[e];
}

// ---------------- gather-mean (bf16 in, bf16 out, fp32 accumulate) ----------------
template <int KH>
__global__ __launch_bounds__(256) void gather_mean_bf16(const u16* __restrict__ F,
                                                        const int* __restrict__ rowptr,
                                                        const int* __restrict__ csr,
                                                        const float* __restrict__ inv,
                                                        u16* __restrict__ Sout, int N) {
    constexpr int CG = KH / 8;       // threads per node (16B chunks)
    constexpr int NPB = 256 / CG;
    const int c = threadIdx.x % CG;
    const int node = blockIdx.x * NPB + threadIdx.x / CG;
    if (node >= N) return;
    const uint4* F4 = (const uint4*)F;
    float a0 = 0, a1 = 0, a2 = 0, a3 = 0, a4 = 0, a5 = 0, a6 = 0, a7 = 0;
    const int beg = rowptr[node], end = rowptr[node + 1];
    int k = beg;
    for (; k + 1 < end; k += 2) {
        uint4 va = F4[(size_t)csr[k] * CG + c];
        uint4 vb = F4[(size_t)csr[k + 1] * CG + c];
        addbf2(va.x, a0, a1); addbf2(va.y, a2, a3);
        addbf2(va.z, a4, a5); addbf2(va.w, a6, a7);
        addbf2(vb.x, a0, a1); addbf2(vb.y, a2, a3);
        addbf2(vb.z, a4, a5); addbf2(vb.w, a6, a7);
    }
    if (k < end) {
        uint4 va = F4[(size_t)csr[k] * CG + c];
        addbf2(va.x, a0, a1); addbf2(va.y, a2, a3);
        addbf2(va.z, a4, a5); addbf2(va.w, a6, a7);
    }
    const float w = inv[node];
    uint4 u;
    u.x = pack2(a0 * w, a1 * w); u.y = pack2(a2 * w, a3 * w);
    u.z = pack2(a4 * w, a5 * w); u.w = pack2(a6 * w, a7 * w);
    ((uint4*)Sout)[(size_t)node * CG + c] = u;
}

// ---------------- weight prep: WT[n][k] = bf16(concat(Wl,Wr)^T) ----------------
template <int KH, int NOUT>
__global__ __launch_bounds__(256) void wt_build(const float* __restrict__ Wl,
                                                const float* __restrict__ Wr,
                                                u16* __restrict__ WT) {
    constexpr int K = 2 * KH;
    int idx = blockIdx.x * 256 + threadIdx.x;
    if (idx >= NOUT * K) return;
    int n = idx / K, k = idx % K;
    float v = (k < KH) ? Wl[(size_t)k * NOUT + n] : Wr[(size_t)(k - KH) * NOUT + n];
    WT[idx] = f2bf(v);
}

// ---------------- MFMA GEMM: H = [S|X] @ W + b, fused BN-stat accumulation ----------------
// 128 x NOUT tile per block (full output width), 4 waves (2x2), BK=32,
// double-buffered global_load_lds with XOR-swizzled LDS (pre-swizzled global source).
template <int KH, int K, int NOUT>
__global__ __launch_bounds__(256, 1) void sage_gemm(const u16* __restrict__ S,
                                                    const u16* __restrict__ X,
                                                    const u16* __restrict__ WT,
                                                    const float* __restrict__ BL,
                                                    u16* __restrict__ Hb,
                                                    float* __restrict__ sums,
                                                    float* __restrict__ sumsq, int M) {
    constexpr int NK = K / 32;
    constexpr int FN = NOUT / 32;              // B fragments per wave (half-width strip)
    constexpr int BUFSZ = 4096 + NOUT * 32;    // u16 per buffer: A 128x32 + B NOUTx32
    __shared__ __align__(16) u16 lds[2][BUFSZ];
    const int t = threadIdx.x;
    const int wid = t >> 6, lane = t & 63;
    const int row0 = blockIdx.x * 128;
    const int wm = wid >> 1, wn = wid & 1;
    const int fr = lane & 15, fc = lane >> 4;

    // stage-side swizzle: lane l writes LDS slot (l&3) of row (l>>2); it must carry
    // logical col-slot (l&3) ^ ((row>>1)&3) = (l&3) ^ ((l>>3)&3)  [16-row groups]
    const int swz8 = (((lane & 3) ^ ((lane >> 3) & 3)) * 8);

    auto stage = [&](int buf, int ks) {
        const int k0 = ks * 32;
        const u16* srcA;
        int kb;
        if (k0 < KH) { srcA = S; kb = k0; } else { srcA = X; kb = k0 - KH; }
#pragma unroll
        for (int jj = 0; jj < 2; ++jj) {
            int j = wid + jj * 4;   // 8 groups of 16 rows = 128 rows
            const u16* g = srcA + (size_t)(row0 + j * 16 + (lane >> 2)) * KH + kb + swz8;
            __builtin_amdgcn_global_load_lds(
                (const __attribute__((address_space(1))) void*)g,
                (__attribute__((address_space(3))) void*)&lds[buf][j * 512], 16, 0, 0);
        }
#pragma unroll
        for (int jj = 0; jj < NOUT / 64; ++jj) {
            int j = wid * (NOUT / 64) + jj;  // NOUT/16 groups of 16 B-rows
            const u16* gb = WT + (size_t)(j * 16 + (lane >> 2)) * K + k0 + swz8;
            __builtin_amdgcn_global_load_lds(
                (const __attribute__((address_space(1))) void*)gb,
                (__attribute__((address_space(3))) void*)&lds[buf][4096 + j * 512], 16, 0, 0);
        }
    };

    f32x4 acc[4][FN] = {};

    stage(0, 0);
    for (int ks = 0; ks < NK; ++ks) {
        __syncthreads();   // drains vmcnt -> buffer ks&1 ready; all waves done reading (ks+1)&1
        if (ks + 1 < NK) stage((ks + 1) & 1, ks + 1);
        const u16* A = &lds[ks & 1][0];
        const u16* B = &lds[ks & 1][4096];
        const int swr = (fr >> 1) & 3;           // read-side swizzle (row>>1)&3, 16-row periodic
        const int kc = (fc ^ swr) * 8;
        bf16x8 a[4], b[FN];
#pragma unroll
        for (int fm = 0; fm < 4; ++fm)
            a[fm] = *(const bf16x8*)&A[(wm * 64 + fm * 16 + fr) * 32 + kc];
#pragma unroll
        for (int fn = 0; fn < FN; ++fn)
            b[fn] = *(const bf16x8*)&B[(wn * (NOUT / 2) + fn * 16 + fr) * 32 + kc];
#pragma unroll
        for (int fm = 0; fm < 4; ++fm)
#pragma unroll
            for (int fn = 0; fn < FN; ++fn)
                acc[fm][fn] = __builtin_amdgcn_mfma_f32_16x16x32_bf16(a[fm], b[fn], acc[fm][fn], 0, 0, 0);
    }

    // epilogue: h = acc + bias; bf16 store; column sums/sumsq (valid rows only)
    const int cw = wn * (NOUT / 2);
    float bias[FN], s[FN], ss[FN];
#pragma unroll
    for (int fn = 0; fn < FN; ++fn) {
        bias[fn] = BL[cw + fn * 16 + fr];
        s[fn] = 0.f; ss[fn] = 0.f;
    }
#pragma unroll
    for (int fm = 0; fm < 4; ++fm) {
#pragma unroll
        for (int q = 0; q < 4; ++q) {
            int r = row0 + wm * 64 + fm * 16 + fc * 4 + q;
            if (r < M) {
#pragma unroll
                for (int fn = 0; fn < FN; ++fn) {
                    float h = acc[fm][fn][q] + bias[fn];
                    Hb[(size_t)r * NOUT + cw + fn * 16 + fr] = f2bf(h);
                    s[fn] += h; ss[fn] += h * h;
                }
            }
        }
    }
#pragma unroll
    for (int fn = 0; fn < FN; ++fn) {
        float sv = s[fn], sq = ss[fn];
        sv += __shfl_xor(sv, 16); sv += __shfl_xor(sv, 32);
        sq += __shfl_xor(sq, 16); sq += __shfl_xor(sq, 32);
        if (fc == 0) {
            atomicAdd(&sums[cw + fn * 16 + fr], sv);
            atomicAdd(&sumsq[cw + fn * 16 + fr], sq);
        }
    }
}

// ---------------- BN finalize ----------------
template <int M>
__global__ void bn_finalize(const float* __restrict__ sums, const float* __restrict__ sumsq,
                            const float* __restrict__ g, const float* __restrict__ beta,
                            float* __restrict__ scale, float* __restrict__ shift, int nrows) {
    int j = threadIdx.x;
    if (j >= M) return;
    float mean = sums[j] / nrows;
    float var = fmaxf(sumsq[j] / nrows - mean * mean, 0.f);
    float sc = g[j] * rsqrtf(var + BN_EPS);
    scale[j] = sc;
    shift[j] = beta[j] - mean * sc;
}

// ---------------- BN apply + ReLU (bf16 -> bf16) ----------------
template <int M>
__global__ __launch_bounds__(256) void bn_relu_bf16(const u16* __restrict__ Hb,
                                                    const float* __restrict__ scale,
                                                    const float* __restrict__ shift,
                                                    u16* __restrict__ Ob, int n8) {
    const uint4* H4 = (const uint4*)Hb;
    uint4* O4 = (uint4*)Ob;
    const float4* sc4 = (const float4*)scale;
    const float4* sh4 = (const float4*)shift;
    for (int i = blockIdx.x * blockDim.x + threadIdx.x; i < n8; i += gridDim.x * blockDim.x) {
        int jg = i % (M / 8);
        uint4 v = H4[i];
        float4 s0 = sc4[jg * 2], s1 = sc4[jg * 2 + 1];
        float4 b0 = sh4[jg * 2], b1 = sh4[jg * 2 + 1];
        float x0, x1, x2, x3, x4, x5, x6, x7;
        bf2(v.x, x0, x1); bf2(v.y, x2, x3); bf2(v.z, x4, x5); bf2(v.w, x6, x7);
        x0 = fmaxf(fmaf(x0, s0.x, b0.x), 0.f);
        x1 = fmaxf(fmaf(x1, s0.y, b0.y), 0.f);
        x2 = fmaxf(fmaf(x2, s0.z, b0.z), 0.f);
        x3 = fmaxf(fmaf(x3, s0.w, b0.w), 0.f);
        x4 = fmaxf(fmaf(x4, s1.x, b1.x), 0.f);
        x5 = fmaxf(fmaf(x5, s1.y, b1.y), 0.f);
        x6 = fmaxf(fmaf(x6, s1.z, b1.z), 0.f);
        x7 = fmaxf(fmaf(x7, s1.w, b1.w), 0.f);
        uint4 u;
        u.x = pack2(x0, x1); u.y = pack2(x2, x3);
        u.z = pack2(x4, x5); u.w = pack2(x6, x7);
        O4[i] = u;
    }
}

// ---------------- head: out = H3 @ wh + bh ----------------
__global__ __launch_bounds__(256) void head_bf16_v2(const u16* __restrict__ H3,
                                                    const float* __restrict__ wh,
                                                    const float* __restrict__ bh,
                                                    float* __restrict__ out, int n) {
    int i = blockIdx.x * blockDim.x + threadIdx.x;
    if (i >= n) return;
    const uint4* h4 = (const uint4*)(H3 + (size_t)i * 64);
    float acc = bh[0];
#pragma unroll
    for (int c = 0; c < 8; ++c) {
        uint4 v = h4[c];
        float x0, x1, x2, x3, x4, x5, x6, x7;
        bf2(v.x, x0, x1); bf2(v.y, x2, x3); bf2(v.z, x4, x5); bf2(v.w, x6, x7);
        const float* w = wh + c * 8;
        acc += x0 * w[0] + x1 * w[1] + x2 * w[2] + x3 * w[3] +
               x4 * w[4] + x5 * w[5] + x6 * w[6] + x7 * w[7];
    }
    out[i] = acc;
}

// ---------------- launch ----------------
extern "C" void kernel_launch(void* const* d_in, const int* in_sizes, int n_in,
                              void* d_out, int out_size, void* d_ws, size_t ws_size,
                              hipStream_t stream) {
    const int N = N_NODES, E = N_EDGES;
    const float* x   = (const float*)d_in[0];
    const int*   ei  = (const int*)d_in[1];
    const int*   src = ei;
    const int*   dst = ei + E;
    const float* w1l = (const float*)d_in[2];
    const float* b1l = (const float*)d_in[3];
    const float* w1r = (const float*)d_in[4];
    const float* g1  = (const float*)d_in[5];
    const float* be1 = (const float*)d_in[6];
    const float* w2l = (const float*)d_in[7];
    const float* b2l = (const float*)d_in[8];
    const float* w2r = (const float*)d_in[9];
    const float* g2  = (const float*)d_in[10];
    const float* be2 = (const float*)d_in[11];
    const float* w3l = (const float*)d_in[12];
    const float* b3l = (const float*)d_in[13];
    const float* w3r = (const float*)d_in[14];
    const float* g3  = (const float*)d_in[15];
    const float* be3 = (const float*)d_in[16];
    const float* wh  = (const float*)d_in[17];
    const float* bh  = (const float*)d_in[18];
    float* out = (float*)d_out;

    // ---- workspace layout (256B-aligned regions) ----
    char* base = (char*)d_ws;
    size_t off = 0;
    auto alloc = [&](size_t bytes) -> void* {
        void* r = base + off;
        off += (bytes + 255) & ~(size_t)255;
        return r;
    };
    const int NB = (N + 255) / 256;  // 196 scan blocks
    int*   rowptr = (int*)alloc((N + 8) * sizeof(int));
    int*   csr    = (int*)alloc((size_t)E * sizeof(int));
    int*   ints2  = (int*)alloc(2 * (size_t)N * sizeof(int));  // deg_i | cursor
    int*   deg_i  = ints2;
    int*   cursor = ints2 + N;
    int*   bsum   = (int*)alloc(256 * sizeof(int));
    float* inv    = (float*)alloc(N * sizeof(float));
    u16*   xb     = (u16*)alloc((size_t)NP * 256 * 2);
    u16*   sB     = (u16*)alloc((size_t)NP * 256 * 2);
    u16*   h1b    = (u16*)alloc((size_t)NP * 256 * 2);
    u16*   h2b    = (u16*)alloc((size_t)NP * 128 * 2);
    u16*   h3b    = (u16*)alloc((size_t)NP * 64 * 2);
    u16*   hpre   = (u16*)alloc((size_t)NP * 256 * 2);
    u16*   wt     = (u16*)alloc((size_t)256 * 512 * 2);
    float* stats  = (float*)alloc(1024 * sizeof(float));
    float* sums = stats, *sumsq = stats + 256, *scale = stats + 512, *shift = stats + 768;

    auto zero = [&](void* p, size_t nfloats) {
        int n4 = (int)(nfloats / 4);
        int blocks = (n4 + 255) / 256;
        if (blocks > 2048) blocks = 2048;
        fill_zero<<<blocks, 256, 0, stream>>>((float*)p, n4);
    };

    // ---- prep: x -> bf16 ----
    f32_to_bf16<<<2048, 256, 0, stream>>>(x, xb, N * 256 / 8);

    // ---- CSR build (3-phase parallel scan) ----
    zero(ints2, 2 * (size_t)N);  // deg_i + cursor in one dispatch
    deg_count<<<(E + 255) / 256, 256, 0, stream>>>(dst, deg_i, E);
    scan_phase1<<<NB, 256, 0, stream>>>(deg_i, rowptr, bsum, N);
    scan_phase2<<<1, 256, 0, stream>>>(bsum, rowptr, NB, N);
    scan_phase3<<<NB, 256, 0, stream>>>(rowptr, bsum, deg_i, inv, N);
    csr_fill<<<(E + 255) / 256, 256, 0, stream>>>(src, dst, rowptr, cursor, csr, E);

    const int MB = NP / 128;  // 391

    // ---- layer 1: K=512 (256|256) -> 256 ----
    gather_mean_bf16<256><<<(N * 32 + 255) / 256, 256, 0, stream>>>(xb, rowptr, csr, inv, sB, N);
    wt_build<256, 256><<<(256 * 512 + 255) / 256, 256, 0, stream>>>(w1l, w1r, wt);
    zero(sums, 512);
    sage_gemm<256, 512, 256><<<MB, 256, 0, stream>>>(sB, xb, wt, b1l, hpre, sums, sumsq, N);
    bn_finalize<256><<<1, 256, 0, stream>>>(sums, sumsq, g1, be1, scale, shift, N);
    bn_relu_bf16<256><<<2048, 256, 0, stream>>>(hpre, scale, shift, h1b, N * 256 / 8);

    // ---- layer 2: K=512 (256|256) -> 128 ----
    gather_mean_bf16<256><<<(N * 32 + 255) / 256, 256, 0, stream>>>(h1b, rowptr, csr, inv, sB, N);
    wt_build<256, 128><<<(128 * 512 + 255) / 256, 256, 0, stream>>>(w2l, w2r, wt);
    zero(sums, 512);
    sage_gemm<256, 512, 128><<<MB, 256, 0, stream>>>(sB, h1b, wt, b2l, hpre, sums, sumsq, N);
    bn_finalize<128><<<1, 128, 0, stream>>>(sums, sumsq, g2, be2, scale, shift, N);
    bn_relu_bf16<128><<<2048, 256, 0, stream>>>(hpre, scale, shift, h2b, N * 128 / 8);

    // ---- layer 3: K=256 (128|128) -> 64 ----
    gather_mean_bf16<128><<<(N * 16 + 255) / 256, 256, 0, stream>>>(h2b, rowptr, csr, inv, sB, N);
    wt_build<128, 64><<<(64 * 256 + 255) / 256, 256, 0, stream>>>(w3l, w3r, wt);
    zero(sums, 512);
    sage_gemm<128, 256, 64><<<MB, 256, 0, stream>>>(sB, h2b, wt, b3l, hpre, sums, sumsq, N);
    bn_finalize<64><<<1, 64, 0, stream>>>(sums, sumsq, g3, be3, scale, shift, N);
    bn_relu_bf16<64><<<2048, 256, 0, stream>>>(hpre, scale, shift, h3b, N * 64 / 8);

    // ---- head ----
    head_bf16_v2<<<(N + 255) / 256, 256, 0, stream>>>(h3b, wh, bh, out, N);
}